// Round 1
// baseline (1302.533 us; speedup 1.0000x reference)
//
#include <hip/hip_runtime.h>

// ---------------- types & helpers ----------------
typedef __bf16 bf16x8 __attribute__((ext_vector_type(8)));
typedef float  f32x4  __attribute__((ext_vector_type(4)));

__device__ __forceinline__ unsigned short f2bf(float f) {
    unsigned u = __float_as_uint(f);
    u += 0x7fffu + ((u >> 16) & 1u);   // RNE
    return (unsigned short)(u >> 16);
}

__device__ __forceinline__ void gld_lds16(const void* g, void* l) {
    __builtin_amdgcn_global_load_lds(
        (const __attribute__((address_space(1))) void*)g,
        (__attribute__((address_space(3))) void*)l,
        16, 0, 0);
}

// ---------------- problem constants ----------------
#define NB  32
#define SQ  256
#define HD  1024
#define ID  4096
#define NEXP 8          // skill experts; index 8 = shared
#define PAIRS (NB * 3)  // (batch, slot) pairs

// workspace layout (bytes)
#define OFF_EID    ((size_t)0)            // 96 int
#define OFF_WGT    ((size_t)512)          // 96 float
#define OFF_XBF    ((size_t)1024)                       // 8192*1024 bf16
#define OFF_GATET  (OFF_XBF   + (size_t)16777216)       // 9*4096*1024 bf16
#define OFF_UPT    (OFF_GATET + (size_t)75497472)
#define OFF_DOWNT  (OFF_UPT   + (size_t)75497472)
#define OFF_ACT    (OFF_DOWNT + (size_t)75497472)       // 96*256*4096 bf16

// ---------------- routing ----------------
__global__ void routing_kernel(const float* __restrict__ logits,
                               int* __restrict__ eid, float* __restrict__ wgt) {
    int b = threadIdx.x;
    if (b < NB) {
        float l[NEXP];
        for (int j = 0; j < NEXP; ++j) l[j] = logits[b * NEXP + j];
        int a0 = 0;
        for (int j = 1; j < NEXP; ++j) if (l[j] > l[a0]) a0 = j;
        int a1 = -1;
        for (int j = 0; j < NEXP; ++j) {
            if (j == a0) continue;
            if (a1 < 0 || l[j] > l[a1]) a1 = j;
        }
        // renormalized top-2 softmax == 2-way softmax over the top-2 logits
        float w0 = 1.0f / (1.0f + expf(l[a1] - l[a0]));
        eid[b * 3 + 0] = a0;  wgt[b * 3 + 0] = w0;
        eid[b * 3 + 1] = a1;  wgt[b * 3 + 1] = 1.0f - w0;
        eid[b * 3 + 2] = NEXP; wgt[b * 3 + 2] = 1.0f;   // shared
    }
}

// ---------------- x fp32 -> bf16 ----------------
__global__ void xcvt_kernel(const float* __restrict__ x,
                            unsigned short* __restrict__ xb, int n4) {
    int i = blockIdx.x * 256 + threadIdx.x;
    if (i < n4) {
        float4 v = ((const float4*)x)[i];
        union { unsigned short s[4]; uint2 u; } p;
        p.s[0] = f2bf(v.x); p.s[1] = f2bf(v.y);
        p.s[2] = f2bf(v.z); p.s[3] = f2bf(v.w);
        ((uint2*)xb)[i] = p.u;
    }
}

// ---------------- weight transpose+convert: [R][C] fp32 -> [C][R] bf16 ----------------
__global__ void transpose_cvt(const float* __restrict__ skill,
                              const float* __restrict__ shared_m,
                              unsigned short* __restrict__ out, int R, int C) {
    const int e = blockIdx.z;                       // 0..8
    const float* src = (e < NEXP) ? (skill + (size_t)e * R * C) : shared_m;
    unsigned short* dst = out + (size_t)e * R * C;  // [C][R]
    const int c0 = blockIdx.x * 64;
    const int r0 = blockIdx.y * 64;
    __shared__ unsigned short t[64][66];
    const int tid = threadIdx.x;
    const int lr = tid >> 4;            // 0..15
    const int lc = (tid & 15) * 4;
    for (int it = 0; it < 4; ++it) {
        int r = lr + it * 16;
        float4 v = *(const float4*)(src + (size_t)(r0 + r) * C + c0 + lc);
        t[r][lc + 0] = f2bf(v.x);
        t[r][lc + 1] = f2bf(v.y);
        t[r][lc + 2] = f2bf(v.z);
        t[r][lc + 3] = f2bf(v.w);
    }
    __syncthreads();
    const int oc = tid >> 2;            // out row (original col), 0..63
    const int k0 = (tid & 3) * 16;      // 16 elems along original rows
    unsigned int pk[8];
    for (int j = 0; j < 8; ++j) {
        unsigned int lo = t[k0 + 2 * j + 0][oc];
        unsigned int hi = t[k0 + 2 * j + 1][oc];
        pk[j] = lo | (hi << 16);
    }
    unsigned short* dp = dst + (size_t)(c0 + oc) * R + r0 + k0;
    ((uint4*)dp)[0] = make_uint4(pk[0], pk[1], pk[2], pk[3]);
    ((uint4*)dp)[1] = make_uint4(pk[4], pk[5], pk[6], pk[7]);
}

// ---------------- stage1: act = gelu(x@gate) * (x@up) * w  (bf16 out) ----------------
__global__ __launch_bounds__(256, 2) void stage1_gateup(
    const unsigned short* __restrict__ xbf,     // [8192][1024]
    const unsigned short* __restrict__ gateT,   // [9][4096][1024]
    const unsigned short* __restrict__ upT,
    const int* __restrict__ eid, const float* __restrict__ wgt,
    unsigned short* __restrict__ act)           // [96][256][4096]
{
    const int nt = blockIdx.x;   // 0..31  (I tiles)
    const int mt = blockIdx.y;   // 0..1   (token tiles)
    const int p  = blockIdx.z;   // 0..95  (b,slot)
    const int b  = p / 3;
    const int e  = eid[p];
    const float w = wgt[p];

    __shared__ __align__(16) unsigned short lds[3 * 128 * 64];
    unsigned short* La = lds;
    unsigned short* Lg = lds + 8192;
    unsigned short* Lu = lds + 16384;

    const int tid  = threadIdx.x;
    const int wave = tid >> 6;
    const int lane = tid & 63;
    const int wm = (wave >> 1) * 64;
    const int wn = (wave & 1) * 64;

    const unsigned short* Abase = xbf   + (size_t)(b * SQ + mt * 128) * HD;
    const unsigned short* Gbase = gateT + ((size_t)e * ID + nt * 128) * HD;
    const unsigned short* Ubase = upT   + ((size_t)e * ID + nt * 128) * HD;

    const int srow = lane >> 3;
    const int scol = (lane & 7) * 8;

    f32x4 accg[4][4], accu[4][4];
    for (int i = 0; i < 4; ++i)
        for (int j = 0; j < 4; ++j) { accg[i][j] = (f32x4)0.f; accu[i][j] = (f32x4)0.f; }

    const int lrow = lane & 15;
    const int kq   = (lane >> 4) * 8;

    for (int k0 = 0; k0 < HD; k0 += 64) {
        for (int q = 0; q < 4; ++q) {
            const int seg = wave * 4 + q;
            const size_t roff = (size_t)(seg * 8 + srow);
            gld_lds16(Abase + roff * HD + k0 + scol, La + seg * 512);
            gld_lds16(Gbase + roff * HD + k0 + scol, Lg + seg * 512);
            gld_lds16(Ubase + roff * HD + k0 + scol, Lu + seg * 512);
        }
        __syncthreads();
        for (int kk = 0; kk < 64; kk += 32) {
            bf16x8 af[4], gf[4], uf[4];
            for (int mf = 0; mf < 4; ++mf)
                af[mf] = *(const bf16x8*)(La + (wm + mf * 16 + lrow) * 64 + kk + kq);
            for (int nf = 0; nf < 4; ++nf) {
                gf[nf] = *(const bf16x8*)(Lg + (wn + nf * 16 + lrow) * 64 + kk + kq);
                uf[nf] = *(const bf16x8*)(Lu + (wn + nf * 16 + lrow) * 64 + kk + kq);
            }
            for (int mf = 0; mf < 4; ++mf)
                for (int nf = 0; nf < 4; ++nf) {
                    accg[mf][nf] = __builtin_amdgcn_mfma_f32_16x16x32_bf16(af[mf], gf[nf], accg[mf][nf], 0, 0, 0);
                    accu[mf][nf] = __builtin_amdgcn_mfma_f32_16x16x32_bf16(af[mf], uf[nf], accu[mf][nf], 0, 0, 0);
                }
        }
        __syncthreads();
    }

    unsigned short* actp = act + (size_t)p * (SQ * ID);
    const int rb = mt * 128 + wm + ((lane >> 4) << 2);
    const int cb = nt * 128 + wn + (lane & 15);
    for (int mf = 0; mf < 4; ++mf)
        for (int nf = 0; nf < 4; ++nf)
            for (int r = 0; r < 4; ++r) {
                float g = accg[mf][nf][r];
                float u = accu[mf][nf][r];
                float t = 0.7978845608028654f * (g + 0.044715f * g * g * g);
                float h = 0.5f * g * (1.0f + tanhf(t)) * u * w;
                actp[(size_t)(rb + mf * 16 + r) * ID + cb + nf * 16] = f2bf(h);
            }
}

// ---------------- stage2: out = sum_slot act_slot @ down_slot  (fp32 out) ----------------
__global__ __launch_bounds__(256, 2) void stage2_down(
    const unsigned short* __restrict__ act,     // [96][256][4096]
    const unsigned short* __restrict__ downT,   // [9][1024][4096]
    const int* __restrict__ eid,
    float* __restrict__ out)                    // [32][256][1024]
{
    const int nt = blockIdx.x;   // 0..7  (H tiles)
    const int mt = blockIdx.y;   // 0..1
    const int b  = blockIdx.z;   // 0..31

    __shared__ __align__(16) unsigned short lds[2 * 128 * 64];
    unsigned short* La = lds;
    unsigned short* Lb = lds + 8192;

    const int tid  = threadIdx.x;
    const int wave = tid >> 6;
    const int lane = tid & 63;
    const int wm = (wave >> 1) * 64;
    const int wn = (wave & 1) * 64;

    const int e0 = eid[b * 3 + 0], e1 = eid[b * 3 + 1], e2 = eid[b * 3 + 2];

    const int srow = lane >> 3;
    const int scol = (lane & 7) * 8;
    const int lrow = lane & 15;
    const int kq   = (lane >> 4) * 8;

    f32x4 acc[4][4];
    for (int i = 0; i < 4; ++i)
        for (int j = 0; j < 4; ++j) acc[i][j] = (f32x4)0.f;

    for (int k0 = 0; k0 < 3 * ID; k0 += 64) {
        const int slot = k0 >> 12;
        const int i0   = k0 & (ID - 1);
        const int e    = (slot == 0) ? e0 : (slot == 1 ? e1 : e2);
        const unsigned short* Abase = act   + ((size_t)(b * 3 + slot) * SQ + mt * 128) * ID + i0;
        const unsigned short* Bbase = downT + ((size_t)e * HD + nt * 128) * ID + i0;
        for (int q = 0; q < 4; ++q) {
            const int seg = wave * 4 + q;
            const size_t roff = (size_t)(seg * 8 + srow);
            gld_lds16(Abase + roff * ID + scol, La + seg * 512);
            gld_lds16(Bbase + roff * ID + scol, Lb + seg * 512);
        }
        __syncthreads();
        for (int kk = 0; kk < 64; kk += 32) {
            bf16x8 af[4], bf[4];
            for (int mf = 0; mf < 4; ++mf)
                af[mf] = *(const bf16x8*)(La + (wm + mf * 16 + lrow) * 64 + kk + kq);
            for (int nf = 0; nf < 4; ++nf)
                bf[nf] = *(const bf16x8*)(Lb + (wn + nf * 16 + lrow) * 64 + kk + kq);
            for (int mf = 0; mf < 4; ++mf)
                for (int nf = 0; nf < 4; ++nf)
                    acc[mf][nf] = __builtin_amdgcn_mfma_f32_16x16x32_bf16(af[mf], bf[nf], acc[mf][nf], 0, 0, 0);
        }
        __syncthreads();
    }

    const int rb = mt * 128 + wm + ((lane >> 4) << 2);
    const int cb = nt * 128 + wn + (lane & 15);
    for (int mf = 0; mf < 4; ++mf)
        for (int nf = 0; nf < 4; ++nf)
            for (int r = 0; r < 4; ++r)
                out[((size_t)b * SQ + rb + mf * 16 + r) * HD + cb + nf * 16] = acc[mf][nf][r];
}

// ---------------- host ----------------
extern "C" void kernel_launch(void* const* d_in, const int* in_sizes, int n_in,
                              void* d_out, int out_size, void* d_ws, size_t ws_size,
                              hipStream_t stream) {
    const float* x        = (const float*)d_in[0];
    const float* logits   = (const float*)d_in[1];
    const float* sk_gate  = (const float*)d_in[2];
    const float* sk_up    = (const float*)d_in[3];
    const float* sk_down  = (const float*)d_in[4];
    const float* sh_gate  = (const float*)d_in[5];
    const float* sh_up    = (const float*)d_in[6];
    const float* sh_down  = (const float*)d_in[7];
    float* out = (float*)d_out;

    char* ws = (char*)d_ws;
    int*            eid   = (int*)(ws + OFF_EID);
    float*          wgt   = (float*)(ws + OFF_WGT);
    unsigned short* xbf   = (unsigned short*)(ws + OFF_XBF);
    unsigned short* gateT = (unsigned short*)(ws + OFF_GATET);
    unsigned short* upT   = (unsigned short*)(ws + OFF_UPT);
    unsigned short* downT = (unsigned short*)(ws + OFF_DOWNT);
    unsigned short* act   = (unsigned short*)(ws + OFF_ACT);

    routing_kernel<<<1, 64, 0, stream>>>(logits, eid, wgt);

    const int n4 = (NB * SQ * HD) / 4;
    xcvt_kernel<<<(n4 + 255) / 256, 256, 0, stream>>>(x, xbf, n4);

    // gate/up: [1024][4096] -> [4096][1024];  down: [4096][1024] -> [1024][4096]
    transpose_cvt<<<dim3(ID / 64, HD / 64, 9), 256, 0, stream>>>(sk_gate, sh_gate, gateT, HD, ID);
    transpose_cvt<<<dim3(ID / 64, HD / 64, 9), 256, 0, stream>>>(sk_up,   sh_up,   upT,   HD, ID);
    transpose_cvt<<<dim3(HD / 64, ID / 64, 9), 256, 0, stream>>>(sk_down, sh_down, downT, ID, HD);

    stage1_gateup<<<dim3(ID / 128, SQ / 128, PAIRS), 256, 0, stream>>>(xbf, gateT, upT, eid, wgt, act);
    stage2_down<<<dim3(HD / 128, SQ / 128, NB), 256, 0, stream>>>(act, downT, eid, out);
}